// Round 8
// baseline (2486.002 us; speedup 1.0000x reference)
//
#include <hip/hip_runtime.h>
#include <hip/hip_fp16.h>
#include <cstdint>
#include <cstddef>

#define T_STEPS 512
#define HID 40
#define GATES 120

typedef _Float16 half8 __attribute__((ext_vector_type(8)));
typedef _Float16 fp16x2 __attribute__((ext_vector_type(2)));
typedef float f32x4 __attribute__((ext_vector_type(4)));

// Single-wave-block "barrier": lanes lockstep; only LDS completion ordering needed.
__device__ __forceinline__ void wavesync() { asm volatile("s_waitcnt lgkmcnt(0)" ::: "memory"); }
__device__ __forceinline__ float bperm(int srclane, float v) {
    return __int_as_float(__builtin_amdgcn_ds_bpermute(srclane << 2, __float_as_int(v)));
}
__device__ __forceinline__ float sigm(float x) { return 1.f / (1.f + __expf(-x)); }

#if __has_builtin(__builtin_amdgcn_fdot2)
__device__ __forceinline__ float fdot2(fp16x2 a, fp16x2 b, float c) {
    return __builtin_amdgcn_fdot2(a, b, c, false);
}
#else
__device__ __forceinline__ float fdot2(fp16x2 a, fp16x2 b, float c) {
    return c + (float)a[0] * (float)b[0] + (float)a[1] * (float)b[1];
}
#endif

// ---------------- weight prep (run once, tiny) ----------------
__global__ __launch_bounds__(256) void prep_pad(
    const float* __restrict__ w, const float* __restrict__ b,
    __half* __restrict__ out, int N, int K, int KPAD)
{
    const int idx = blockIdx.x * 256 + threadIdx.x;
    const int n = idx / KPAD, k = idx - n * KPAD;
    float v = 0.f;
    if (n < N) {
        if (k < K) v = w[n * K + k];
        else if (k == KPAD - 1) v = b[n];
    }
    out[idx] = __float2half(v);
}

__global__ __launch_bounds__(256) void prep_eff(
    const float* __restrict__ g_wih, const float* __restrict__ g_bih,
    const float* __restrict__ w2, const float* __restrict__ b2,
    __half* __restrict__ out)
{
    const int li  = blockIdx.y;
    const int idx = blockIdx.x * 256 + threadIdx.x;   // over 128*64
    const int n = idx >> 6, k = idx & 63;
    float v = 0.f;
    if (n < GATES) {
        const float* wrow = g_wih + ((size_t)(li + 1) * GATES + n) * HID;
        if (k < HID) {
            for (int j = 0; j < HID; ++j) v += wrow[j] * w2[((size_t)li * HID + j) * HID + k];
        } else if (k == 63) {
            v = g_bih[(size_t)(li + 1) * GATES + n];
            for (int j = 0; j < HID; ++j) v += wrow[j] * b2[(size_t)li * HID + j];
        }
    }
    out[(size_t)li * 128 * 64 + idx] = __float2half(v);
}

__global__ __launch_bounds__(256) void prep_f16cvt(
    const float* __restrict__ w, _Float16* __restrict__ o, int n)
{
    const int i = blockIdx.x * 256 + threadIdx.x;
    if (i < n) o[i] = (_Float16)w[i];
}

// ---------------- MFMA gate precompute (verified in R7) ----------------
// MODE 0: in = fp32 x [rows][20], K=20(pad32), bias slot k=31.
// MODE 1: in = f16 rows (h at [0:40] of stride-120 rows), K=40(pad64), bias k=63.
// MODE 2: MLP GEMM1 (w1pad[48][64]) + leaky -> swizzled LDS -> GEMM2 (K pad64).
template<int MODE>
__global__ __launch_bounds__(256) void precomp_mfma(
    const void* in_, _Float16* xp,
    const _Float16* __restrict__ wihpad,  // [128][KP]
    const _Float16* __restrict__ w1pad,   // [48][64] (MODE 2 only)
    int nrows)
{
    __shared__ _Float16 s_v[4][1024];     // per-wave 2KB swizzled V tile [16][64]
    const int tid  = threadIdx.x;
    const int wid  = tid >> 6, lane = tid & 63;
    const int g    = lane >> 4, r = lane & 15;

    constexpr int KP  = (MODE == 0) ? 32 : 64;
    constexpr int NKS = KP / 32;

    half8 bw[8][NKS];
    #pragma unroll
    for (int t = 0; t < 8; ++t)
        #pragma unroll
        for (int ks = 0; ks < NKS; ++ks)
            bw[t][ks] = *reinterpret_cast<const half8*>(wihpad + (t * 16 + r) * KP + ks * 32 + g * 8);

    half8 b1f[3][2];
    char* myv = nullptr;
    if constexpr (MODE == 2) {
        #pragma unroll
        for (int t = 0; t < 3; ++t)
            #pragma unroll
            for (int ks = 0; ks < 2; ++ks)
                b1f[t][ks] = *reinterpret_cast<const half8*>(w1pad + (t * 16 + r) * 64 + ks * 32 + g * 8);
        myv = (char*)&s_v[wid][0];
        uint4 z; z.x = z.y = z.z = z.w = 0u;
        *reinterpret_cast<uint4*>(myv + lane * 32)      = z;
        *reinterpret_cast<uint4*>(myv + lane * 32 + 16) = z;
        wavesync();
        if (lane < 16)
            *reinterpret_cast<_Float16*>(myv + lane * 128 + (126 ^ ((lane & 7) << 4))) = (_Float16)1.f;
        wavesync();
    }

    const int w0     = blockIdx.x * 4 + wid;
    const int stride = gridDim.x * 64;

    for (int rb = w0 * 16; rb < nrows; rb += stride) {
        half8 a0, a1;
        if constexpr (MODE == 0) {
            const float* xr = (const float*)in_ + (size_t)(rb + r) * 20;
            if (g < 2) {
                const float4 v0 = *reinterpret_cast<const float4*>(xr + g * 8);
                const float4 v1 = *reinterpret_cast<const float4*>(xr + g * 8 + 4);
                a0[0]=(_Float16)v0.x; a0[1]=(_Float16)v0.y; a0[2]=(_Float16)v0.z; a0[3]=(_Float16)v0.w;
                a0[4]=(_Float16)v1.x; a0[5]=(_Float16)v1.y; a0[6]=(_Float16)v1.z; a0[7]=(_Float16)v1.w;
            } else if (g == 2) {
                const float4 v0 = *reinterpret_cast<const float4*>(xr + 16);
                a0[0]=(_Float16)v0.x; a0[1]=(_Float16)v0.y; a0[2]=(_Float16)v0.z; a0[3]=(_Float16)v0.w;
                a0[4]=(_Float16)0.f; a0[5]=(_Float16)0.f; a0[6]=(_Float16)0.f; a0[7]=(_Float16)0.f;
            } else {
                #pragma unroll
                for (int j = 0; j < 8; ++j) a0[j] = (_Float16)0.f;
                a0[7] = (_Float16)1.f;    // bias slot k=31
            }
        } else {
            const _Float16* hr = (const _Float16*)in_ + (size_t)(rb + r) * GATES;
            a0 = *reinterpret_cast<const half8*>(hr + g * 8);          // k 0..31
            if (g == 0) {
                a1 = *reinterpret_cast<const half8*>(hr + 32);         // k 32..39
            } else {
                #pragma unroll
                for (int j = 0; j < 8; ++j) a1[j] = (_Float16)0.f;
                if (g == 3) a1[7] = (_Float16)1.f;                     // bias slot k=63
            }
        }

        if constexpr (MODE == 2) {
            #pragma unroll
            for (int t = 0; t < 3; ++t) {
                f32x4 acc = {0.f, 0.f, 0.f, 0.f};
                acc = __builtin_amdgcn_mfma_f32_16x16x32_f16(a0, b1f[t][0], acc, 0, 0, 0);
                acc = __builtin_amdgcn_mfma_f32_16x16x32_f16(a1, b1f[t][1], acc, 0, 0, 0);
                const int n2 = (t * 16 + r) * 2;                       // byte col
                #pragma unroll
                for (int reg = 0; reg < 4; ++reg) {
                    const int m = g * 4 + reg;
                    float v = acc[reg];
                    v = v > 0.f ? v : 0.01f * v;
                    *reinterpret_cast<_Float16*>(myv + m * 128 + (n2 ^ ((m & 7) << 4))) = (_Float16)v;
                }
            }
            wavesync();
            const int sw = (r & 7) << 4;
            a0 = *reinterpret_cast<const half8*>(myv + r * 128 + ((g * 16) ^ sw));
            a1 = *reinterpret_cast<const half8*>(myv + r * 128 + ((64 + g * 16) ^ sw));
        }

        #pragma unroll
        for (int t = 0; t < 8; ++t) {
            f32x4 acc = {0.f, 0.f, 0.f, 0.f};
            acc = __builtin_amdgcn_mfma_f32_16x16x32_f16(a0, bw[t][0], acc, 0, 0, 0);
            if constexpr (NKS == 2)
                acc = __builtin_amdgcn_mfma_f32_16x16x32_f16(a1, bw[t][1], acc, 0, 0, 0);
            const int n = t * 16 + r;
            if (n < GATES) {
                #pragma unroll
                for (int reg = 0; reg < 4; ++reg) {
                    const int m = g * 4 + reg;
                    xp[(size_t)(rb + m) * GATES + n] = (_Float16)acc[reg];
                }
            }
        }
    }
}

// ---------------- recurrence: f16 weights in VGPRs + v_dot2_f32_f16 ----------------
// One wave per element. Lane l<40: gA=r_l, gB=n_l(80+l); lane 40..63: gA=z_{l-40};
// lanes 40..55: gB=z_{l-16}. r/n lane-local; z via one ds_bpermute pair.
// Weights: whh16 [120][40] f16 -> 40 VGPRs total for both gates (fits the budget,
// no per-step reloads). h carried in f32; LDS broadcast copy is f16 (dot inputs).
__global__ __launch_bounds__(64) void gru_rec(
    __half* xp,                         // [CB, T, 120], h written into [t][0:40]
    const _Float16* __restrict__ whh16, // [120][40] f16
    const float* __restrict__ bhh)      // [120]
{
    __shared__ __align__(16) _Float16 s_h[64];

    const int lane = threadIdx.x;
    const int e    = blockIdx.x;

    const int gA = lane;
    const int gB = (lane < 40) ? (80 + lane) : ((lane < 56) ? (24 + lane) : lane);

    fp16x2 wA[20], wB[20];
    {
        const fp16x2* wp = reinterpret_cast<const fp16x2*>(whh16);
        #pragma unroll
        for (int k = 0; k < 20; ++k) { wA[k] = wp[gA * 20 + k]; wB[k] = wp[gB * 20 + k]; }
    }
    const float bhA = bhh[gA], bhB = bhh[gB];

    __half* xpb = xp + (size_t)e * T_STEPS * GATES;

    float hreg = 0.f;
    s_h[lane] = (_Float16)0.f;

    __half a0 = xpb[gA],         c0 = xpb[gB];
    __half a1 = xpb[GATES + gA], c1 = xpb[GATES + gB];
    wavesync();

    for (int t = 0; t < T_STEPS; ++t) {
        __half a2 = a0, c2 = c0;
        if (t + 2 < T_STEPS) {
            a2 = xpb[(size_t)(t + 2) * GATES + gA];
            c2 = xpb[(size_t)(t + 2) * GATES + gB];
        }

        // uniform-broadcast h (f16): 5 x ds_read_b128, conflict-free
        const half8* hp = reinterpret_cast<const half8*>(s_h);
        const half8 h0 = hp[0], h1 = hp[1], h2 = hp[2], h3 = hp[3], h4 = hp[4];
        fp16x2 q[20];
        q[ 0]=(fp16x2){h0[0],h0[1]}; q[ 1]=(fp16x2){h0[2],h0[3]};
        q[ 2]=(fp16x2){h0[4],h0[5]}; q[ 3]=(fp16x2){h0[6],h0[7]};
        q[ 4]=(fp16x2){h1[0],h1[1]}; q[ 5]=(fp16x2){h1[2],h1[3]};
        q[ 6]=(fp16x2){h1[4],h1[5]}; q[ 7]=(fp16x2){h1[6],h1[7]};
        q[ 8]=(fp16x2){h2[0],h2[1]}; q[ 9]=(fp16x2){h2[2],h2[3]};
        q[10]=(fp16x2){h2[4],h2[5]}; q[11]=(fp16x2){h2[6],h2[7]};
        q[12]=(fp16x2){h3[0],h3[1]}; q[13]=(fp16x2){h3[2],h3[3]};
        q[14]=(fp16x2){h3[4],h3[5]}; q[15]=(fp16x2){h3[6],h3[7]};
        q[16]=(fp16x2){h4[0],h4[1]}; q[17]=(fp16x2){h4[2],h4[3]};
        q[18]=(fp16x2){h4[4],h4[5]}; q[19]=(fp16x2){h4[6],h4[7]};

        float fA0=0.f, fA1=0.f, fA2=0.f, fA3=0.f;
        float fB0=0.f, fB1=0.f, fB2=0.f, fB3=0.f;
        #pragma unroll
        for (int k = 0; k < 20; k += 4) {
            fA0 = fdot2(q[k+0], wA[k+0], fA0);
            fA1 = fdot2(q[k+1], wA[k+1], fA1);
            fA2 = fdot2(q[k+2], wA[k+2], fA2);
            fA3 = fdot2(q[k+3], wA[k+3], fA3);
            fB0 = fdot2(q[k+0], wB[k+0], fB0);
            fB1 = fdot2(q[k+1], wB[k+1], fB1);
            fB2 = fdot2(q[k+2], wB[k+2], fB2);
            fB3 = fdot2(q[k+3], wB[k+3], fB3);
        }
        const float shA = bhA + ((fA0 + fA2) + (fA1 + fA3));
        const float shB = bhB + ((fB0 + fB2) + (fB1 + fB3));
        const float xA  = __half2float(a0);
        const float xB  = __half2float(c0);
        const float sumA = xA + shA;
        const float sumB = xB + shB;
        const float zA = bperm(40 + lane, sumA);
        const float zB = bperm(16 + lane, sumB);

        if (lane < HID) {
            const float rr  = sigm(sumA);
            const float z   = sigm((lane < 24) ? zA : zB);
            const float pre = xB + rr * shB;          // x_n + r*h_n (biases included)
            const float ex  = __expf(-2.f * pre);
            const float n   = (1.f - ex) / (1.f + ex);
            hreg = (1.f - z) * n + z * hreg;
            s_h[lane] = (_Float16)hreg;
            xpb[(size_t)t * GATES + lane] = __float2half(hreg);
        }
        a0 = a1; c0 = c1; a1 = a2; c1 = c2;
        wavesync();
    }
}

// ---------------- head (unchanged) ----------------
__global__ __launch_bounds__(256) void final_head(
    const __half* __restrict__ hbase,  // xpbuf + (T-1)*GATES
    float* __restrict__ outp,          // [CB]
    const float* __restrict__ w1, const float* __restrict__ b1,
    const float* __restrict__ wl, const float* __restrict__ bl, int n)
{
    __shared__ float s_w1[HID][HID + 1];
    __shared__ float s_b1[HID];
    __shared__ float s_wl[HID];
    for (int i = threadIdx.x; i < HID * HID; i += 256) s_w1[i / HID][i % HID] = w1[i];
    if (threadIdx.x < HID) { s_b1[threadIdx.x] = b1[threadIdx.x]; s_wl[threadIdx.x] = wl[threadIdx.x]; }
    __syncthreads();
    const int e = blockIdx.x * 256 + threadIdx.x;
    if (e >= n) return;

    alignas(16) __half hx[HID];
    const uint4* hr = reinterpret_cast<const uint4*>(hbase + (size_t)e * T_STEPS * GATES);
    #pragma unroll
    for (int q = 0; q < HID / 8; ++q) reinterpret_cast<uint4*>(hx)[q] = hr[q];
    float h[HID];
    #pragma unroll
    for (int k = 0; k < HID; ++k) h[k] = __half2float(hx[k]);

    float acc = bl[0];
    #pragma unroll
    for (int u = 0; u < HID; ++u) {
        float a = s_b1[u];
        #pragma unroll
        for (int d = 0; d < HID; ++d) a += s_w1[u][d] * h[d];
        a = a > 0.f ? a : 0.01f * a;
        acc += a * s_wl[u];
    }
    outp[e] = 1.f / (1.f + __expf(-acc));
}

extern "C" void kernel_launch(void* const* d_in, const int* in_sizes, int n_in,
                              void* d_out, int out_size, void* d_ws, size_t ws_size,
                              hipStream_t stream)
{
    const float* x      = (const float*)d_in[0];
    const float* g0_wih = (const float*)d_in[1];
    const float* g0_whh = (const float*)d_in[2];
    const float* g0_bih = (const float*)d_in[3];
    const float* g0_bhh = (const float*)d_in[4];
    const float* g_wih  = (const float*)d_in[5];   // [4,120,40]
    const float* g_whh  = (const float*)d_in[6];   // [4,120,40]
    const float* g_bih  = (const float*)d_in[7];   // [4,120]
    const float* g_bhh  = (const float*)d_in[8];   // [4,120]
    const float* mlp_w1 = (const float*)d_in[9];   // [4,40,40]
    const float* mlp_b1 = (const float*)d_in[10];  // [4,40]
    const float* mlp_w2 = (const float*)d_in[11];  // [3,40,40]
    const float* mlp_b2 = (const float*)d_in[12];  // [3,40]
    const float* w_last = (const float*)d_in[13];  // [1,40]
    const float* b_last = (const float*)d_in[14];  // [1]

    const int B = in_sizes[0] / (T_STEPS * 20);
    float* out = (float*)d_out;

    // ws (halfs): [w1pad 3*3072][effpad 3*8192][g0pad 4096][g1pad 8192][whh16 5*4800] then xp
    __half* wsz    = (__half*)d_ws;
    __half* w1pad  = wsz;                       // 9216
    __half* effpad = wsz + 3 * 3072;            // 24576
    __half* g0pad  = wsz + 9216 + 3 * 8192;     // 4096
    __half* g1pad  = g0pad + 4096;              // 8192
    _Float16* whh16 = (_Float16*)(wsz + 46080); // 24000
    _Float16* xpbuf = (_Float16*)(wsz + 70080); // 140160 B of weights, 16B aligned
    const size_t ws_rem = ws_size - 70080 * sizeof(__half);

    for (int li = 0; li < 3; ++li)
        prep_pad<<<dim3(12), dim3(256), 0, stream>>>(
            mlp_w1 + li * 1600, mlp_b1 + li * 40, w1pad + li * 3072, 40, 40, 64);
    prep_pad<<<dim3(16), dim3(256), 0, stream>>>(g0_wih, g0_bih, g0pad, 120, 20, 32);
    prep_pad<<<dim3(32), dim3(256), 0, stream>>>(g_wih, g_bih, g1pad, 120, 40, 64);
    prep_eff<<<dim3(32, 3), dim3(256), 0, stream>>>(g_wih, g_bih, mlp_w2, mlp_b2, effpad);
    prep_f16cvt<<<dim3(19), dim3(256), 0, stream>>>(g0_whh, whh16, 4800);
    prep_f16cvt<<<dim3(75), dim3(256), 0, stream>>>(g_whh, whh16 + 4800, 19200);

    const size_t per_e = (size_t)T_STEPS * GATES * sizeof(__half);  // 240 B/row
    int CB = B;
    while ((size_t)CB * per_e > ws_rem && CB > 64) CB >>= 1;

    for (int c = 0; c < B; c += CB) {
        const int  nrows = CB * T_STEPS;
        const dim3 pgrd(nrows / 512), pblk(256);
        const dim3 rgrd(CB), rblk(64);
        const float* xc = x + (size_t)c * T_STEPS * 20;

        precomp_mfma<0><<<pgrd, pblk, 0, stream>>>(
            xc, xpbuf, (const _Float16*)g0pad, nullptr, nrows);
        gru_rec<<<rgrd, rblk, 0, stream>>>((__half*)xpbuf, whh16, g0_bhh);

        precomp_mfma<1><<<pgrd, pblk, 0, stream>>>(
            xpbuf, xpbuf, (const _Float16*)g1pad, nullptr, nrows);
        gru_rec<<<rgrd, rblk, 0, stream>>>((__half*)xpbuf, whh16 + 4800, g_bhh + 0 * 120);

        for (int li = 0; li < 3; ++li) {
            precomp_mfma<2><<<pgrd, pblk, 0, stream>>>(
                xpbuf, xpbuf, (const _Float16*)(effpad + li * 8192),
                (const _Float16*)(w1pad + li * 3072), nrows);
            gru_rec<<<rgrd, rblk, 0, stream>>>(
                (__half*)xpbuf, whh16 + 4800 + (li + 1) * 4800, g_bhh + (li + 1) * 120);
        }

        final_head<<<dim3((CB + 255) / 256), dim3(256), 0, stream>>>(
            (const __half*)(xpbuf + (size_t)(T_STEPS - 1) * GATES), out + c,
            mlp_w1 + 3 * 1600, mlp_b1 + 3 * 40, w_last, b_last, CB);
    }
}

// Round 9
// 2483.567 us; speedup vs baseline: 1.0010x; 1.0010x over previous
//
#include <hip/hip_runtime.h>
#include <hip/hip_fp16.h>
#include <cstdint>
#include <cstddef>

#define T_STEPS 512
#define HID 40
#define GATES 120

typedef _Float16 half8 __attribute__((ext_vector_type(8)));
typedef _Float16 fp16x2 __attribute__((ext_vector_type(2)));
typedef float f32x4 __attribute__((ext_vector_type(4)));

// Single-wave-block "barrier": lanes lockstep; only LDS completion ordering needed.
__device__ __forceinline__ void wavesync() { asm volatile("s_waitcnt lgkmcnt(0)" ::: "memory"); }
__device__ __forceinline__ float bperm(int srclane, float v) {
    return __int_as_float(__builtin_amdgcn_ds_bpermute(srclane << 2, __float_as_int(v)));
}
__device__ __forceinline__ float sigm(float x) { return 1.f / (1.f + __expf(-x)); }

#if __has_builtin(__builtin_amdgcn_fdot2)
__device__ __forceinline__ float fdot2(fp16x2 a, fp16x2 b, float c) {
    return __builtin_amdgcn_fdot2(a, b, c, false);
}
#else
__device__ __forceinline__ float fdot2(fp16x2 a, fp16x2 b, float c) {
    return c + (float)a[0] * (float)b[0] + (float)a[1] * (float)b[1];
}
#endif

// ---------------- weight prep (run once, tiny) ----------------
__global__ __launch_bounds__(256) void prep_pad(
    const float* __restrict__ w, const float* __restrict__ b,
    __half* __restrict__ out, int N, int K, int KPAD)
{
    const int idx = blockIdx.x * 256 + threadIdx.x;
    const int n = idx / KPAD, k = idx - n * KPAD;
    float v = 0.f;
    if (n < N) {
        if (k < K) v = w[n * K + k];
        else if (k == KPAD - 1) v = b[n];
    }
    out[idx] = __float2half(v);
}

__global__ __launch_bounds__(256) void prep_eff(
    const float* __restrict__ g_wih, const float* __restrict__ g_bih,
    const float* __restrict__ w2, const float* __restrict__ b2,
    __half* __restrict__ out)
{
    const int li  = blockIdx.y;
    const int idx = blockIdx.x * 256 + threadIdx.x;   // over 128*64
    const int n = idx >> 6, k = idx & 63;
    float v = 0.f;
    if (n < GATES) {
        const float* wrow = g_wih + ((size_t)(li + 1) * GATES + n) * HID;
        if (k < HID) {
            for (int j = 0; j < HID; ++j) v += wrow[j] * w2[((size_t)li * HID + j) * HID + k];
        } else if (k == 63) {
            v = g_bih[(size_t)(li + 1) * GATES + n];
            for (int j = 0; j < HID; ++j) v += wrow[j] * b2[(size_t)li * HID + j];
        }
    }
    out[(size_t)li * 128 * 64 + idx] = __float2half(v);
}

__global__ __launch_bounds__(256) void prep_f16cvt(
    const float* __restrict__ w, _Float16* __restrict__ o, int n)
{
    const int i = blockIdx.x * 256 + threadIdx.x;
    if (i < n) o[i] = (_Float16)w[i];
}

// ---------------- MFMA gate precompute (verified in R7) ----------------
// MODE 0: in = fp32 x [rows][20], K=20(pad32), bias slot k=31.
// MODE 1: in = f16 rows (h at [0:40] of stride-120 rows), K=40(pad64), bias k=63.
// MODE 2: MLP GEMM1 (w1pad[48][64]) + leaky -> swizzled LDS -> GEMM2 (K pad64).
template<int MODE>
__global__ __launch_bounds__(256) void precomp_mfma(
    const void* in_, _Float16* xp,
    const _Float16* __restrict__ wihpad,  // [128][KP]
    const _Float16* __restrict__ w1pad,   // [48][64] (MODE 2 only)
    int nrows)
{
    __shared__ _Float16 s_v[4][1024];     // per-wave 2KB swizzled V tile [16][64]
    const int tid  = threadIdx.x;
    const int wid  = tid >> 6, lane = tid & 63;
    const int g    = lane >> 4, r = lane & 15;

    constexpr int KP  = (MODE == 0) ? 32 : 64;
    constexpr int NKS = KP / 32;

    half8 bw[8][NKS];
    #pragma unroll
    for (int t = 0; t < 8; ++t)
        #pragma unroll
        for (int ks = 0; ks < NKS; ++ks)
            bw[t][ks] = *reinterpret_cast<const half8*>(wihpad + (t * 16 + r) * KP + ks * 32 + g * 8);

    half8 b1f[3][2];
    char* myv = nullptr;
    if constexpr (MODE == 2) {
        #pragma unroll
        for (int t = 0; t < 3; ++t)
            #pragma unroll
            for (int ks = 0; ks < 2; ++ks)
                b1f[t][ks] = *reinterpret_cast<const half8*>(w1pad + (t * 16 + r) * 64 + ks * 32 + g * 8);
        myv = (char*)&s_v[wid][0];
        uint4 z; z.x = z.y = z.z = z.w = 0u;
        *reinterpret_cast<uint4*>(myv + lane * 32)      = z;
        *reinterpret_cast<uint4*>(myv + lane * 32 + 16) = z;
        wavesync();
        if (lane < 16)
            *reinterpret_cast<_Float16*>(myv + lane * 128 + (126 ^ ((lane & 7) << 4))) = (_Float16)1.f;
        wavesync();
    }

    const int w0     = blockIdx.x * 4 + wid;
    const int stride = gridDim.x * 64;

    for (int rb = w0 * 16; rb < nrows; rb += stride) {
        half8 a0, a1;
        if constexpr (MODE == 0) {
            const float* xr = (const float*)in_ + (size_t)(rb + r) * 20;
            if (g < 2) {
                const float4 v0 = *reinterpret_cast<const float4*>(xr + g * 8);
                const float4 v1 = *reinterpret_cast<const float4*>(xr + g * 8 + 4);
                a0[0]=(_Float16)v0.x; a0[1]=(_Float16)v0.y; a0[2]=(_Float16)v0.z; a0[3]=(_Float16)v0.w;
                a0[4]=(_Float16)v1.x; a0[5]=(_Float16)v1.y; a0[6]=(_Float16)v1.z; a0[7]=(_Float16)v1.w;
            } else if (g == 2) {
                const float4 v0 = *reinterpret_cast<const float4*>(xr + 16);
                a0[0]=(_Float16)v0.x; a0[1]=(_Float16)v0.y; a0[2]=(_Float16)v0.z; a0[3]=(_Float16)v0.w;
                a0[4]=(_Float16)0.f; a0[5]=(_Float16)0.f; a0[6]=(_Float16)0.f; a0[7]=(_Float16)0.f;
            } else {
                #pragma unroll
                for (int j = 0; j < 8; ++j) a0[j] = (_Float16)0.f;
                a0[7] = (_Float16)1.f;    // bias slot k=31
            }
        } else {
            const _Float16* hr = (const _Float16*)in_ + (size_t)(rb + r) * GATES;
            a0 = *reinterpret_cast<const half8*>(hr + g * 8);          // k 0..31
            if (g == 0) {
                a1 = *reinterpret_cast<const half8*>(hr + 32);         // k 32..39
            } else {
                #pragma unroll
                for (int j = 0; j < 8; ++j) a1[j] = (_Float16)0.f;
                if (g == 3) a1[7] = (_Float16)1.f;                     // bias slot k=63
            }
        }

        if constexpr (MODE == 2) {
            #pragma unroll
            for (int t = 0; t < 3; ++t) {
                f32x4 acc = {0.f, 0.f, 0.f, 0.f};
                acc = __builtin_amdgcn_mfma_f32_16x16x32_f16(a0, b1f[t][0], acc, 0, 0, 0);
                acc = __builtin_amdgcn_mfma_f32_16x16x32_f16(a1, b1f[t][1], acc, 0, 0, 0);
                const int n2 = (t * 16 + r) * 2;                       // byte col
                #pragma unroll
                for (int reg = 0; reg < 4; ++reg) {
                    const int m = g * 4 + reg;
                    float v = acc[reg];
                    v = v > 0.f ? v : 0.01f * v;
                    *reinterpret_cast<_Float16*>(myv + m * 128 + (n2 ^ ((m & 7) << 4))) = (_Float16)v;
                }
            }
            wavesync();
            const int sw = (r & 7) << 4;
            a0 = *reinterpret_cast<const half8*>(myv + r * 128 + ((g * 16) ^ sw));
            a1 = *reinterpret_cast<const half8*>(myv + r * 128 + ((64 + g * 16) ^ sw));
        }

        #pragma unroll
        for (int t = 0; t < 8; ++t) {
            f32x4 acc = {0.f, 0.f, 0.f, 0.f};
            acc = __builtin_amdgcn_mfma_f32_16x16x32_f16(a0, bw[t][0], acc, 0, 0, 0);
            if constexpr (NKS == 2)
                acc = __builtin_amdgcn_mfma_f32_16x16x32_f16(a1, bw[t][1], acc, 0, 0, 0);
            const int n = t * 16 + r;
            if (n < GATES) {
                #pragma unroll
                for (int reg = 0; reg < 4; ++reg) {
                    const int m = g * 4 + reg;
                    xp[(size_t)(rb + m) * GATES + n] = (_Float16)acc[reg];
                }
            }
        }
    }
}

// ---------------- recurrence: f16 weights PINNED in VGPRs + v_dot2_f32_f16 ----------------
// One wave per element. Lane l<40: gA=r_l, gB=n_l(80+l); lane 40..63: gA=z_{l-40};
// lanes 40..55: gB=z_{l-16}. r/n lane-local; z via one ds_bpermute pair.
// The in-loop empty asm "+v" redefines each weight dword every iteration, so the
// compiler CANNOT re-materialize them by reloading from global (R8 failure mode:
// VGPR_Count=36, loads sunk into the loop, 440us).
__global__ __launch_bounds__(64) void gru_rec(
    __half* xp,                         // [CB, T, 120], h written into [t][0:40]
    const _Float16* __restrict__ whh16, // [120][40] f16
    const float* __restrict__ bhh)      // [120]
{
    __shared__ __align__(16) _Float16 s_h[64];

    const int lane = threadIdx.x;
    const int e    = blockIdx.x;

    const int gA = lane;
    const int gB = (lane < 40) ? (80 + lane) : ((lane < 56) ? (24 + lane) : lane);

    uint32_t wA[20], wB[20];
    {
        const uint32_t* wp = reinterpret_cast<const uint32_t*>(whh16);
        #pragma unroll
        for (int k = 0; k < 20; ++k) { wA[k] = wp[gA * 20 + k]; wB[k] = wp[gB * 20 + k]; }
    }
    const float bhA = bhh[gA], bhB = bhh[gB];

    __half* xpb = xp + (size_t)e * T_STEPS * GATES;

    float hreg = 0.f;
    s_h[lane] = (_Float16)0.f;

    __half a0 = xpb[gA],         c0 = xpb[gB];
    __half a1 = xpb[GATES + gA], c1 = xpb[GATES + gB];
    const __half* pfA = xpb + 2 * GATES + gA;     // prefetch cursors (t+2)
    const __half* pfB = xpb + 2 * GATES + gB;
    __half*       pst = xpb + lane;               // store cursor (row t)
    wavesync();

    for (int t = 0; t < T_STEPS; ++t) {
        // Pin weights: redefine via empty asm so reloads are impossible.
        #pragma unroll
        for (int k = 0; k < 20; ++k)
            asm volatile("" : "+v"(wA[k]), "+v"(wB[k]));

        __half a2 = a0, c2 = c0;
        if (t + 2 < T_STEPS) { a2 = *pfA; c2 = *pfB; pfA += GATES; pfB += GATES; }

        // uniform-broadcast h (f16): 5 x ds_read_b128, conflict-free; sub-register
        // fp16x2 extraction via shufflevector (no v_mov unpack).
        const half8* hp = reinterpret_cast<const half8*>(s_h);
        const half8 h0 = hp[0], h1 = hp[1], h2 = hp[2], h3 = hp[3], h4 = hp[4];
        fp16x2 q[20];
        q[ 0]=__builtin_shufflevector(h0,h0,0,1); q[ 1]=__builtin_shufflevector(h0,h0,2,3);
        q[ 2]=__builtin_shufflevector(h0,h0,4,5); q[ 3]=__builtin_shufflevector(h0,h0,6,7);
        q[ 4]=__builtin_shufflevector(h1,h1,0,1); q[ 5]=__builtin_shufflevector(h1,h1,2,3);
        q[ 6]=__builtin_shufflevector(h1,h1,4,5); q[ 7]=__builtin_shufflevector(h1,h1,6,7);
        q[ 8]=__builtin_shufflevector(h2,h2,0,1); q[ 9]=__builtin_shufflevector(h2,h2,2,3);
        q[10]=__builtin_shufflevector(h2,h2,4,5); q[11]=__builtin_shufflevector(h2,h2,6,7);
        q[12]=__builtin_shufflevector(h3,h3,0,1); q[13]=__builtin_shufflevector(h3,h3,2,3);
        q[14]=__builtin_shufflevector(h3,h3,4,5); q[15]=__builtin_shufflevector(h3,h3,6,7);
        q[16]=__builtin_shufflevector(h4,h4,0,1); q[17]=__builtin_shufflevector(h4,h4,2,3);
        q[18]=__builtin_shufflevector(h4,h4,4,5); q[19]=__builtin_shufflevector(h4,h4,6,7);

        float fA0=0.f, fA1=0.f, fA2=0.f, fA3=0.f;
        float fB0=0.f, fB1=0.f, fB2=0.f, fB3=0.f;
        #pragma unroll
        for (int k = 0; k < 20; k += 4) {
            fA0 = fdot2(q[k+0], __builtin_bit_cast(fp16x2, wA[k+0]), fA0);
            fA1 = fdot2(q[k+1], __builtin_bit_cast(fp16x2, wA[k+1]), fA1);
            fA2 = fdot2(q[k+2], __builtin_bit_cast(fp16x2, wA[k+2]), fA2);
            fA3 = fdot2(q[k+3], __builtin_bit_cast(fp16x2, wA[k+3]), fA3);
            fB0 = fdot2(q[k+0], __builtin_bit_cast(fp16x2, wB[k+0]), fB0);
            fB1 = fdot2(q[k+1], __builtin_bit_cast(fp16x2, wB[k+1]), fB1);
            fB2 = fdot2(q[k+2], __builtin_bit_cast(fp16x2, wB[k+2]), fB2);
            fB3 = fdot2(q[k+3], __builtin_bit_cast(fp16x2, wB[k+3]), fB3);
        }
        const float shA = bhA + ((fA0 + fA2) + (fA1 + fA3));
        const float shB = bhB + ((fB0 + fB2) + (fB1 + fB3));
        const float xA  = __half2float(a0);
        const float xB  = __half2float(c0);
        const float sumA = xA + shA;
        const float sumB = xB + shB;
        const float zA = bperm(40 + lane, sumA);
        const float zB = bperm(16 + lane, sumB);

        if (lane < HID) {
            const float rr  = sigm(sumA);
            const float z   = sigm((lane < 24) ? zA : zB);
            const float pre = xB + rr * shB;          // x_n + r*h_n (biases included)
            const float ex  = __expf(-2.f * pre);
            const float n   = (1.f - ex) / (1.f + ex);
            hreg = (1.f - z) * n + z * hreg;
            s_h[lane] = (_Float16)hreg;
            *pst = __float2half(hreg);
        }
        pst += GATES;
        a0 = a1; c0 = c1; a1 = a2; c1 = c2;
        wavesync();
    }
}

// ---------------- head (unchanged) ----------------
__global__ __launch_bounds__(256) void final_head(
    const __half* __restrict__ hbase,  // xpbuf + (T-1)*GATES
    float* __restrict__ outp,          // [CB]
    const float* __restrict__ w1, const float* __restrict__ b1,
    const float* __restrict__ wl, const float* __restrict__ bl, int n)
{
    __shared__ float s_w1[HID][HID + 1];
    __shared__ float s_b1[HID];
    __shared__ float s_wl[HID];
    for (int i = threadIdx.x; i < HID * HID; i += 256) s_w1[i / HID][i % HID] = w1[i];
    if (threadIdx.x < HID) { s_b1[threadIdx.x] = b1[threadIdx.x]; s_wl[threadIdx.x] = wl[threadIdx.x]; }
    __syncthreads();
    const int e = blockIdx.x * 256 + threadIdx.x;
    if (e >= n) return;

    alignas(16) __half hx[HID];
    const uint4* hr = reinterpret_cast<const uint4*>(hbase + (size_t)e * T_STEPS * GATES);
    #pragma unroll
    for (int q = 0; q < HID / 8; ++q) reinterpret_cast<uint4*>(hx)[q] = hr[q];
    float h[HID];
    #pragma unroll
    for (int k = 0; k < HID; ++k) h[k] = __half2float(hx[k]);

    float acc = bl[0];
    #pragma unroll
    for (int u = 0; u < HID; ++u) {
        float a = s_b1[u];
        #pragma unroll
        for (int d = 0; d < HID; ++d) a += s_w1[u][d] * h[d];
        a = a > 0.f ? a : 0.01f * a;
        acc += a * s_wl[u];
    }
    outp[e] = 1.f / (1.f + __expf(-acc));
}

extern "C" void kernel_launch(void* const* d_in, const int* in_sizes, int n_in,
                              void* d_out, int out_size, void* d_ws, size_t ws_size,
                              hipStream_t stream)
{
    const float* x      = (const float*)d_in[0];
    const float* g0_wih = (const float*)d_in[1];
    const float* g0_whh = (const float*)d_in[2];
    const float* g0_bih = (const float*)d_in[3];
    const float* g0_bhh = (const float*)d_in[4];
    const float* g_wih  = (const float*)d_in[5];   // [4,120,40]
    const float* g_whh  = (const float*)d_in[6];   // [4,120,40]
    const float* g_bih  = (const float*)d_in[7];   // [4,120]
    const float* g_bhh  = (const float*)d_in[8];   // [4,120]
    const float* mlp_w1 = (const float*)d_in[9];   // [4,40,40]
    const float* mlp_b1 = (const float*)d_in[10];  // [4,40]
    const float* mlp_w2 = (const float*)d_in[11];  // [3,40,40]
    const float* mlp_b2 = (const float*)d_in[12];  // [3,40]
    const float* w_last = (const float*)d_in[13];  // [1,40]
    const float* b_last = (const float*)d_in[14];  // [1]

    const int B = in_sizes[0] / (T_STEPS * 20);
    float* out = (float*)d_out;

    // ws (halfs): [w1pad 3*3072][effpad 3*8192][g0pad 4096][g1pad 8192][whh16 5*4800] then xp
    __half* wsz    = (__half*)d_ws;
    __half* w1pad  = wsz;                       // 9216
    __half* effpad = wsz + 3 * 3072;            // 24576
    __half* g0pad  = wsz + 9216 + 3 * 8192;     // 4096
    __half* g1pad  = g0pad + 4096;              // 8192
    _Float16* whh16 = (_Float16*)(wsz + 46080); // 24000
    _Float16* xpbuf = (_Float16*)(wsz + 70080); // 140160 B of weights, 16B aligned
    const size_t ws_rem = ws_size - 70080 * sizeof(__half);

    for (int li = 0; li < 3; ++li)
        prep_pad<<<dim3(12), dim3(256), 0, stream>>>(
            mlp_w1 + li * 1600, mlp_b1 + li * 40, w1pad + li * 3072, 40, 40, 64);
    prep_pad<<<dim3(16), dim3(256), 0, stream>>>(g0_wih, g0_bih, g0pad, 120, 20, 32);
    prep_pad<<<dim3(32), dim3(256), 0, stream>>>(g_wih, g_bih, g1pad, 120, 40, 64);
    prep_eff<<<dim3(32, 3), dim3(256), 0, stream>>>(g_wih, g_bih, mlp_w2, mlp_b2, effpad);
    prep_f16cvt<<<dim3(19), dim3(256), 0, stream>>>(g0_whh, whh16, 4800);
    prep_f16cvt<<<dim3(75), dim3(256), 0, stream>>>(g_whh, whh16 + 4800, 19200);

    const size_t per_e = (size_t)T_STEPS * GATES * sizeof(__half);  // 240 B/row
    int CB = B;
    while ((size_t)CB * per_e > ws_rem && CB > 64) CB >>= 1;

    for (int c = 0; c < B; c += CB) {
        const int  nrows = CB * T_STEPS;
        const dim3 pgrd(nrows / 512), pblk(256);
        const dim3 rgrd(CB), rblk(64);
        const float* xc = x + (size_t)c * T_STEPS * 20;

        precomp_mfma<0><<<pgrd, pblk, 0, stream>>>(
            xc, xpbuf, (const _Float16*)g0pad, nullptr, nrows);
        gru_rec<<<rgrd, rblk, 0, stream>>>((__half*)xpbuf, whh16, g0_bhh);

        precomp_mfma<1><<<pgrd, pblk, 0, stream>>>(
            xpbuf, xpbuf, (const _Float16*)g1pad, nullptr, nrows);
        gru_rec<<<rgrd, rblk, 0, stream>>>((__half*)xpbuf, whh16 + 4800, g_bhh + 0 * 120);

        for (int li = 0; li < 3; ++li) {
            precomp_mfma<2><<<pgrd, pblk, 0, stream>>>(
                xpbuf, xpbuf, (const _Float16*)(effpad + li * 8192),
                (const _Float16*)(w1pad + li * 3072), nrows);
            gru_rec<<<rgrd, rblk, 0, stream>>>(
                (__half*)xpbuf, whh16 + 4800 + (li + 1) * 4800, g_bhh + (li + 1) * 120);
        }

        final_head<<<dim3((CB + 255) / 256), dim3(256), 0, stream>>>(
            (const __half*)(xpbuf + (size_t)(T_STEPS - 1) * GATES), out + c,
            mlp_w1 + 3 * 1600, mlp_b1 + 3 * 40, w_last, b_last, CB);
    }
}